// Round 1
// baseline (152.439 us; speedup 1.0000x reference)
//
#include <hip/hip_runtime.h>
#include <hip/hip_bf16.h>
#include <stdint.h>
#include <stddef.h>

#define GN 6144
#define GH 4
#define KSPLIT 4
#define JRANGE (GN / KSPLIT)   /* 1536 */
#define WAVES 4

typedef float  f32x4  __attribute__((ext_vector_type(4)));
typedef float  f32x16 __attribute__((ext_vector_type(16)));
typedef __bf16 bf16x4 __attribute__((ext_vector_type(4)));
typedef __bf16 bf16x8 __attribute__((ext_vector_type(8)));

__device__ __forceinline__ float fast_exp2(float x) {
#if __has_builtin(__builtin_amdgcn_exp2f)
  return __builtin_amdgcn_exp2f(x);
#else
  return exp2f(x);
#endif
}

// ---------------- K0: convert h_mat -> bf16, weight -> transposed bf16 ----
__global__ __launch_bounds__(256) void gat_cvt(const float* __restrict__ hm,
                                               const float* __restrict__ wgt,
                                               __bf16* __restrict__ hbf,
                                               __bf16* __restrict__ wT) {
  const int b = blockIdx.x, t = threadIdx.x;
  if (b < 768) {
    const int idx = (b * 256 + t) * 4;
    f32x4 v = *(const f32x4*)(hm + idx);
    bf16x4 o;
    o[0] = (__bf16)v[0]; o[1] = (__bf16)v[1];
    o[2] = (__bf16)v[2]; o[3] = (__bf16)v[3];
    *(bf16x4*)(hbf + idx) = o;
  } else if (t < 128) {
    const int c = t;                       // wT[c][k] = wgt[k][c]
    bf16x8* dst = (bf16x8*)(wT + c * 128);
#pragma unroll
    for (int q = 0; q < 16; ++q) {
      bf16x8 v;
#pragma unroll
      for (int e = 0; e < 8; ++e) v[e] = (__bf16)wgt[(q * 8 + e) * 128 + c];
      dst[q] = v;
    }
  }
}

// ---------------- K1: wh GEMM (bf16 MFMA) + whT bf16 + lp2/lc2 ----------
__global__ __launch_bounds__(256) void gat_wh(const __bf16* __restrict__ hbf,
                                              const __bf16* __restrict__ wT,
                                              const float* __restrict__ aw,
                                              __bf16* __restrict__ whT,
                                              float* __restrict__ lp2,
                                              float* __restrict__ lc2) {
  __shared__ float ldsC[64 * 132];         // padded: stride 132 breaks bank conflicts
  const int t = threadIdx.x;
  const int wave = t >> 6, lane = t & 63;
  const int col = lane & 31, kg = lane >> 5;
  const int n0 = blockIdx.x * 64;
  const int rowHalf = (wave & 1) * 32;
  const int colBase = (wave >> 1) * 64;

  f32x16 acc[2];
#pragma unroll
  for (int ct = 0; ct < 2; ++ct)
#pragma unroll
    for (int i = 0; i < 16; ++i) acc[ct][i] = 0.0f;

#pragma unroll
  for (int kk = 0; kk < 8; ++kk) {
    const int k = kk * 16 + kg * 8;
    bf16x8 af = *(const bf16x8*)(hbf + (size_t)(n0 + rowHalf + col) * 128 + k);
#pragma unroll
    for (int ct = 0; ct < 2; ++ct) {
      bf16x8 bfr = *(const bf16x8*)(wT + (size_t)(colBase + ct * 32 + col) * 128 + k);
      acc[ct] = __builtin_amdgcn_mfma_f32_32x32x16_bf16(af, bfr, acc[ct], 0, 0, 0);
    }
  }
  // C layout: col = lane&31, row = (r&3) + 8*(r>>2) + 4*(lane>>5)
#pragma unroll
  for (int ct = 0; ct < 2; ++ct)
#pragma unroll
    for (int r = 0; r < 16; ++r)
      ldsC[(rowHalf + (r & 3) + 8 * (r >> 2) + 4 * kg) * 132 + colBase + ct * 32 + col] =
          acc[ct][r];
  __syncthreads();

  {  // transposed bf16 store: whT[c][n], 64B contiguous per thread
    const int c = t >> 1, half = t & 1;
    __bf16* dst = whT + (size_t)c * GN + n0 + half * 32;
#pragma unroll
    for (int q = 0; q < 4; ++q) {
      bf16x8 v;
#pragma unroll
      for (int e = 0; e < 8; ++e) v[e] = (__bf16)ldsC[(half * 32 + q * 8 + e) * 132 + c];
      *(bf16x8*)(dst + q * 8) = v;
    }
  }
  {  // lp/lc dots, pre-scaled by log2(e)
    const int nl = t & 63, h = t >> 6;
    float sp = 0.f, sd = 0.f;
#pragma unroll
    for (int f = 0; f < 32; ++f) {
      const float v = ldsC[nl * 132 + h * 32 + f];
      sp = fmaf(v, aw[h * 64 + f], sp);
      sd = fmaf(v, aw[h * 64 + 32 + f], sd);
    }
    const float LOG2E = 1.4426950408889634f;
    lp2[(n0 + nl) * GH + h] = sp * LOG2E;
    lc2[(n0 + nl) * GH + h] = sd * LOG2E;
  }
}

// ---------------- K2: main fused masked-softmax-PV kernel ----------------
__global__ __launch_bounds__(256, 3) void gat_main(const float* __restrict__ adj,
                                                   const __bf16* __restrict__ whT,
                                                   const float* __restrict__ lp2,
                                                   const float* __restrict__ lc2,
                                                   float* __restrict__ out,
                                                   float* __restrict__ denom) {
  __shared__ __align__(16) float lcs[JRANGE * GH];   // 24 KB
  const int t = threadIdx.x;
  const int wave = t >> 6, lane = t & 63;
  const int col = lane & 31, kg = lane >> 5;
  const int n0 = blockIdx.x * 32;
  const int jbase = blockIdx.y * JRANGE;
  const int nrow = n0 + col;

  for (int i = t; i < JRANGE; i += 256)
    ((f32x4*)lcs)[i] = ((const f32x4*)(lc2 + (size_t)jbase * GH))[i];
  __syncthreads();   // only barrier — main loop is barrier-free

  const f32x4 lpv = *(const f32x4*)(lp2 + (size_t)nrow * GH);

  f32x16 acc[GH];
#pragma unroll
  for (int h = 0; h < GH; ++h)
#pragma unroll
    for (int i = 0; i < 16; ++i) acc[h][i] = 0.0f;
  float dreg[GH] = {0.f, 0.f, 0.f, 0.f};

  const float* adjrow = adj + (size_t)nrow * GN;

  for (int tt = 0; tt < JRANGE / (WAVES * 16); ++tt) {
    const int j0 = jbase + (tt * WAVES + wave) * 16;
    const int jl = j0 - jbase + kg * 8;
    // adj: 8 consecutive f32/lane, each 64B line consumed exactly once -> NT
    const f32x4 a0 = __builtin_nontemporal_load((const f32x4*)(adjrow + j0 + kg * 8));
    const f32x4 a1 = __builtin_nontemporal_load((const f32x4*)(adjrow + j0 + kg * 8) + 1);
    bf16x8 bfr[GH];
#pragma unroll
    for (int h = 0; h < GH; ++h)
      bfr[h] = *(const bf16x8*)(whT + (size_t)(h * 32 + col) * GN + j0 + kg * 8);

    bf16x8 afr[GH];
#pragma unroll
    for (int p = 0; p < 4; ++p) {
      const f32x4 lcA = *(const f32x4*)(lcs + (jl + 2 * p) * GH);
      const f32x4 lcB = *(const f32x4*)(lcs + (jl + 2 * p + 1) * GH);
      const float avA = (p < 2) ? a0[(2 * p) & 3] : a1[(2 * p) & 3];
      const float avB = (p < 2) ? a0[(2 * p + 1) & 3] : a1[(2 * p + 1) & 3];
#pragma unroll
      for (int h = 0; h < GH; ++h) {
        const float xA = lpv[h] + lcA[h];
        const float xB = lpv[h] + lcB[h];
        const float eA = avA * fast_exp2(fmaxf(xA, 0.2f * xA));
        const float eB = avB * fast_exp2(fmaxf(xB, 0.2f * xB));
        dreg[h] += eA + eB;
        afr[h][2 * p]     = (__bf16)eA;
        afr[h][2 * p + 1] = (__bf16)eB;
      }
    }
#pragma unroll
    for (int h = 0; h < GH; ++h)
      acc[h] = __builtin_amdgcn_mfma_f32_32x32x16_bf16(afr[h], bfr[h], acc[h], 0, 0, 0);
  }

  // denominator: lanes l and l+32 hold same row, different k-groups
#pragma unroll
  for (int h = 0; h < GH; ++h) {
    const float d = dreg[h] + __shfl_xor(dreg[h], 32);
    if (lane < 32) atomicAdd(denom + (size_t)nrow * GH + h, d);
  }
#pragma unroll
  for (int h = 0; h < GH; ++h)
#pragma unroll
    for (int r = 0; r < 16; ++r) {
      const int rn = n0 + (r & 3) + 8 * (r >> 2) + 4 * kg;
      atomicAdd(out + (size_t)rn * 128 + h * 32 + col, acc[h][r]);
    }
}

// ---------------- K3: divide by softmax denominator ----------------------
__global__ __launch_bounds__(256) void gat_div(float* __restrict__ out,
                                               const float* __restrict__ denom) {
  const int idx = blockIdx.x * 256 + threadIdx.x;  // one f32x4 per thread
  const int n = idx >> 5;
  const int h = (idx & 31) >> 3;
  const float inv = 1.0f / denom[(size_t)n * GH + h];
  f32x4 v = ((f32x4*)out)[idx];
  v *= inv;
  ((f32x4*)out)[idx] = v;
}

extern "C" void kernel_launch(void* const* d_in, const int* in_sizes, int n_in,
                              void* d_out, int out_size, void* d_ws, size_t ws_size,
                              hipStream_t stream) {
  const float* hm  = (const float*)d_in[0];
  const float* adj = (const float*)d_in[1];
  const float* wgt = (const float*)d_in[2];
  const float* aw  = (const float*)d_in[3];
  float* out = (float*)d_out;

  char* ws = (char*)d_ws;
  __bf16* whT  = (__bf16*)ws; ws += (size_t)128 * GN * 2;   // 1.5 MB
  __bf16* hbf  = (__bf16*)ws; ws += (size_t)GN * 128 * 2;   // 1.5 MB
  __bf16* wT   = (__bf16*)ws; ws += 128 * 128 * 2;          // 32 KB
  float* lp2   = (float*)ws;  ws += GN * GH * 4;            // 96 KB
  float* lc2   = (float*)ws;  ws += GN * GH * 4;            // 96 KB
  float* denom = (float*)ws;                                 // 96 KB

  hipMemsetAsync(d_out, 0, (size_t)GN * 128 * 4, stream);
  hipMemsetAsync(denom, 0, (size_t)GN * GH * 4, stream);
  gat_cvt<<<769, 256, 0, stream>>>(hm, wgt, hbf, wT);
  gat_wh<<<96, 256, 0, stream>>>(hbf, wT, aw, whT, lp2, lc2);
  gat_main<<<dim3(192, KSPLIT), 256, 0, stream>>>(adj, whT, lp2, lc2, out, denom);
  gat_div<<<768, 256, 0, stream>>>(out, denom);
}